// Round 4
// baseline (2097.142 us; speedup 1.0000x reference)
//
#include <hip/hip_runtime.h>
#include <math.h>

#define BZ 32
#define FCH 160
#define NMIX 10
#define PCH 100

typedef __attribute__((ext_vector_type(8))) short bf16x8;
typedef __attribute__((ext_vector_type(8))) unsigned short u16x8;
typedef __attribute__((ext_vector_type(4))) unsigned short u16x4;
typedef __attribute__((ext_vector_type(4))) float f32x4;

__device__ __forceinline__ unsigned short f2bf(float f) {
    union { float f; unsigned u; } x; x.f = f;
    return (unsigned short)((x.u + 0x7FFFu + ((x.u >> 16) & 1u)) >> 16);
}
__device__ __forceinline__ void elupair(float v, float& e0, float& e1) {
    if (v > 0.f) { e0 = v; e1 = expm1f(-v); }
    else         { e0 = expm1f(v); e1 = -v; }
}

// ---------------------------------------------------------------------------
// Weight repack via LDS: one block per (nb, o) output row.
// src w[nb][o][Cin][NT] fp32 (row = Cin*NT contiguous) -> dst [nb][o][NT][Cin]
// bf16, optional concat-elu interleave csrc = (k&1)*(Cin/2) + (k>>1).
// ---------------------------------------------------------------------------
__global__ __launch_bounds__(256) void repack_t_k(
    const float* __restrict__ w, unsigned short* __restrict__ wb,
    int Cout, int CoutPad, int Cin, int NT, int ILV)
{
    __shared__ float buf[1920];
    const int tid = threadIdx.x;
    const int blk = blockIdx.x;
    const int o = blk % CoutPad;
    const int nb = blk / CoutPad;
    const int n = Cin * NT;
    if (o < Cout) {
        const float* src = w + ((size_t)nb * Cout + o) * n;
        for (int e = tid; e < n; e += 256) buf[e] = src[e];
    } else {
        for (int e = tid; e < n; e += 256) buf[e] = 0.f;
    }
    __syncthreads();
    unsigned short* dst = wb + (size_t)blk * n;
    for (int tap = 0; tap < NT; ++tap)
        for (int k = tid; k < Cin; k += 256) {
            int csrc = ILV ? ((k & 1) * (Cin >> 1) + (k >> 1)) : k;
            dst[tap * Cin + k] = f2bf(buf[csrc * NT + tap]);
        }
}

// ---------------------------------------------------------------------------
// Fused init: computes u-init AND ul-init AND both CE tensors in one pass.
// Block: 4 output rows x 32 cols of one image (grid 8 x 32). All smp data and
// all init weights staged in LDS. Thread item -> (pixel p, og); outputs
// o = og + 40*t (strided so LDS weight-row reads hit distinct banks; row
// strides 25/13/9 are coprime with 32).
// ---------------------------------------------------------------------------
__global__ __launch_bounds__(256) void init_fused_k(
    const float* __restrict__ smp,
    const float* __restrict__ wu_g, const float* __restrict__ bu_g,
    const float* __restrict__ wd_g, const float* __restrict__ bd_g,
    const float* __restrict__ wr_g, const float* __restrict__ br_g,
    float* __restrict__ u, float* __restrict__ ul,
    unsigned short* __restrict__ ceu, unsigned short* __restrict__ ceul)
{
    __shared__ float xs[4 * 6 * 34];   // [c:4][row:6][col:34], c==3 is ones-mask
    __shared__ float wuL[160 * 25];    // per-o 24 taps, stride 25
    __shared__ float wdL[160 * 13];    // per-o 12 taps, stride 13
    __shared__ float wrL[160 * 9];     // per-o  8 taps, stride 9
    __shared__ float bL[3 * 160];

    const int tid = threadIdx.x;
    const int b = blockIdx.y;
    const int rb = blockIdx.x * 4;

    for (int e = tid; e < 816; e += 256) {
        int c = e / 204;
        int rem = e - c * 204;
        int r = rem / 34;
        int col = rem - r * 34;
        int gr = rb - 2 + r, gc = col - 1;
        float v = 0.f;
        if ((unsigned)gr < 32u && (unsigned)gc < 32u)
            v = (c < 3) ? smp[(((size_t)b * 3 + c) << 10) + (gr << 5) + gc] * 2.f - 1.f : 1.f;
        xs[e] = v;
    }
    for (int e = tid; e < 160 * 24; e += 256) wuL[(e / 24) * 25 + e % 24] = wu_g[e];
    for (int e = tid; e < 160 * 12; e += 256) wdL[(e / 12) * 13 + e % 12] = wd_g[e];
    for (int e = tid; e < 160 * 8;  e += 256) wrL[(e / 8) * 9 + e % 8] = wr_g[e];
    for (int e = tid; e < 160; e += 256) {
        bL[e] = bu_g[e]; bL[160 + e] = bd_g[e]; bL[320 + e] = br_g[e];
    }
    __syncthreads();

    for (int it = 0; it < 20; ++it) {
        int item = tid + it * 256;
        int og = item % 40;
        int p = item / 40;
        int lr = p >> 5, j = p & 31;
        int i = rb + lr;
        size_t pixbase = (size_t)((b << 10) | (i << 5) | j);
#pragma unroll
        for (int t = 0; t < 4; ++t) {
            int o = og + 40 * t;
            // u = down_shift(ds_conv 2x3): taps rows i-2+kh (local lr+kh), cols j-1+kw
            float au = 0.f;
            const float* wo = &wuL[o * 25];
#pragma unroll
            for (int c = 0; c < 4; ++c)
#pragma unroll
                for (int kh = 0; kh < 2; ++kh)
#pragma unroll
                    for (int kw = 0; kw < 3; ++kw)
                        au += wo[c * 6 + kh * 3 + kw] * xs[c * 204 + (lr + kh) * 34 + (j + kw)];
            float uv = (i == 0) ? 0.f : (au + bL[o]);
            // ul ds part: row i-1 (local lr+1), cols j-1+kw
            float ad = 0.f;
            const float* wdp = &wdL[o * 13];
#pragma unroll
            for (int c = 0; c < 4; ++c)
#pragma unroll
                for (int kw = 0; kw < 3; ++kw)
                    ad += wdp[c * 3 + kw] * xs[c * 204 + (lr + 1) * 34 + (j + kw)];
            // ul dr part: rows i-1+kh (local lr+1+kh), col j-1
            float ar = 0.f;
            const float* wrp = &wrL[o * 9];
#pragma unroll
            for (int c = 0; c < 4; ++c)
#pragma unroll
                for (int kh = 0; kh < 2; ++kh)
                    ar += wrp[c * 2 + kh] * xs[c * 204 + (lr + 1 + kh) * 34 + j];
            float ulv = ((i >= 1) ? ad + bL[160 + o] : 0.f) + ((j >= 1) ? ar + bL[320 + o] : 0.f);

            u[pixbase * 160 + o] = uv;
            ul[pixbase * 160 + o] = ulv;
            float e0, e1;
            elupair(uv, e0, e1);
            ((unsigned*)ceu)[pixbase * 160 + o] = (unsigned)f2bf(e0) | ((unsigned)f2bf(e1) << 16);
            elupair(ulv, e0, e1);
            ((unsigned*)ceul)[pixbase * 160 + o] = (unsigned)f2bf(e0) | ((unsigned)f2bf(e1) << 16);
        }
    }
}

// ---------------------------------------------------------------------------
// MFMA implicit-GEMM conv, channel-last activations [b][pix][320].
// (unchanged from round 3 — counters pending)
// ---------------------------------------------------------------------------
template<int KH, int KW, int PT, int PL, bool DUAL, bool GATE, int MBLK>
__global__ __launch_bounds__(256) void conv_mfma_k(
    const unsigned short* __restrict__ cein,
    const unsigned short* __restrict__ wb,
    const unsigned short* __restrict__ cein2,
    const unsigned short* __restrict__ wb2,
    const float* __restrict__ bias, const float* __restrict__ bias2,
    float* __restrict__ resid,
    unsigned short* __restrict__ ceout)
{
    constexpr int NT = KH * KW;
    constexpr int RW = 8 + KH - 1;
    constexpr int CW = 32 + KW - 1;
    constexpr int KCP = 40;
    constexpr int MTILES = MBLK / 16;
    constexpr int MSH = (MBLK == 32) ? 5 : 6;

    __shared__ __align__(16) unsigned short bs[RW * CW * KCP];
    __shared__ __align__(16) unsigned short wsm[NT * MBLK * KCP];

    const int tid = threadIdx.x;
    const int wv = tid >> 6;
    const int lane = tid & 63;
    const int l16 = lane & 15;
    const int quad = lane >> 4;
    const int m0 = blockIdx.x * 32;
    const int bimg = blockIdx.y >> 2;
    const int rowbase = (blockIdx.y & 3) * 8;

    f32x4 acc[MTILES][4];
#pragma unroll
    for (int mt = 0; mt < MTILES; ++mt)
#pragma unroll
        for (int ng = 0; ng < 4; ++ng)
#pragma unroll
            for (int r = 0; r < 4; ++r) acc[mt][ng][r] = 0.f;

    for (int k0 = 0; k0 < 320; k0 += 32) {
        __syncthreads();
        for (int e = tid; e < RW * CW * 4; e += 256) {
            int seg = e & 3;
            int p = e >> 2;
            int r = p / CW;
            int c = p - r * CW;
            int grow = rowbase + r - PT;
            int gcol = c - PL;
            bf16x8 v = {0, 0, 0, 0, 0, 0, 0, 0};
            if (((unsigned)grow < 32u) && ((unsigned)gcol < 32u))
                v = *(const bf16x8*)(cein +
                    (size_t)(((bimg << 10) | (grow << 5) | gcol)) * 320 + k0 + seg * 8);
            *(bf16x8*)(bs + p * KCP + seg * 8) = v;
        }
        for (int e = tid; e < NT * MBLK * 4; e += 256) {
            int seg = e & 3;
            int mm = (e >> 2) & (MBLK - 1);
            int tap = e >> (2 + MSH);
            int o = GATE ? (mm < 32 ? m0 + mm : 128 + m0 + mm) : (m0 + mm);
            bf16x8 v = *(const bf16x8*)(wb + ((size_t)o * NT + tap) * 320 + k0 + seg * 8);
            *(bf16x8*)(wsm + (tap * MBLK + mm) * KCP + seg * 8) = v;
        }
        __syncthreads();
#pragma unroll
        for (int tap = 0; tap < NT; ++tap) {
            const int kh = tap / KW, kw = tap % KW;
            bf16x8 af[MTILES];
#pragma unroll
            for (int mt = 0; mt < MTILES; ++mt)
                af[mt] = *(const bf16x8*)&wsm[(tap * MBLK + mt * 16 + l16) * KCP + quad * 8];
#pragma unroll
            for (int ng = 0; ng < 4; ++ng) {
                int rl = 2 * wv + (ng >> 1) + kh;
                int cc = (ng & 1) * 16 + l16 + kw;
                bf16x8 bfr = *(const bf16x8*)&bs[(rl * CW + cc) * KCP + quad * 8];
#pragma unroll
                for (int mt = 0; mt < MTILES; ++mt)
                    acc[mt][ng] = __builtin_amdgcn_mfma_f32_16x16x32_bf16(af[mt], bfr, acc[mt][ng], 0, 0, 0);
            }
        }
    }

    if (DUAL) {
        for (int k0 = 0; k0 < 320; k0 += 32) {
            __syncthreads();
            for (int e = tid; e < 8 * 32 * 4; e += 256) {
                int seg = e & 3;
                int p = e >> 2;
                int r = p >> 5, c = p & 31;
                bf16x8 v = *(const bf16x8*)(cein2 +
                    (size_t)(((bimg << 10) | ((rowbase + r) << 5) | c)) * 320 + k0 + seg * 8);
                *(bf16x8*)(bs + (r * CW + c) * KCP + seg * 8) = v;
            }
            for (int e = tid; e < MBLK * 4; e += 256) {
                int seg = e & 3;
                int mm = e >> 2;
                bf16x8 v = *(const bf16x8*)(wb2 + (size_t)(m0 + mm) * 320 + k0 + seg * 8);
                *(bf16x8*)(wsm + mm * KCP + seg * 8) = v;
            }
            __syncthreads();
            bf16x8 af[MTILES];
#pragma unroll
            for (int mt = 0; mt < MTILES; ++mt)
                af[mt] = *(const bf16x8*)&wsm[(mt * 16 + l16) * KCP + quad * 8];
#pragma unroll
            for (int ng = 0; ng < 4; ++ng) {
                int rl = 2 * wv + (ng >> 1);
                int cc = (ng & 1) * 16 + l16;
                bf16x8 bfr = *(const bf16x8*)&bs[(rl * CW + cc) * KCP + quad * 8];
#pragma unroll
                for (int mt = 0; mt < MTILES; ++mt)
                    acc[mt][ng] = __builtin_amdgcn_mfma_f32_16x16x32_bf16(af[mt], bfr, acc[mt][ng], 0, 0, 0);
            }
        }
    }

    constexpr int MOUT = GATE ? MTILES / 2 : MTILES;
#pragma unroll
    for (int mt = 0; mt < MOUT; ++mt) {
        int ob = m0 + mt * 16 + quad * 4;
        f32x4 bv = *(const f32x4*)(bias + ob);
        f32x4 bv2;
        if (DUAL) bv2 = *(const f32x4*)(bias2 + ob);
        f32x4 bg;
        if (GATE) bg = *(const f32x4*)(bias + ob + 160);
#pragma unroll
        for (int ng = 0; ng < 4; ++ng) {
            int i = rowbase + 2 * wv + (ng >> 1);
            int j = (ng & 1) * 16 + l16;
            size_t pb = (size_t)((bimg << 10) | (i << 5) | j);
            if (!GATE) {
                u16x8 st;
#pragma unroll
                for (int r = 0; r < 4; ++r) {
                    float v = acc[mt][ng][r] + bv[r] + (DUAL ? bv2[r] : 0.f);
                    float e0, e1; elupair(v, e0, e1);
                    st[2 * r] = f2bf(e0); st[2 * r + 1] = f2bf(e1);
                }
                *(u16x8*)(ceout + pb * 320 + 2 * ob) = st;
            } else {
                f32x4 rv = *(const f32x4*)(resid + pb * 160 + ob);
                u16x8 st;
#pragma unroll
                for (int r = 0; r < 4; ++r) {
                    float g1 = acc[mt][ng][r] + bv[r];
                    float g2 = acc[mt + MTILES / 2][ng][r] + bg[r];
                    float v = rv[r] + g1 / (1.f + expf(-g2));
                    rv[r] = v;
                    float e0, e1; elupair(v, e0, e1);
                    st[2 * r] = f2bf(e0); st[2 * r + 1] = f2bf(e1);
                }
                *(f32x4*)(resid + pb * 160 + ob) = rv;
                *(u16x8*)(ceout + pb * 320 + 2 * ob) = st;
            }
        }
    }
}

// ---------------------------------------------------------------------------
// nin_out: params = elu(ul) @ W^T + b, K=160, M padded to 128.
// NOW writes params channel-LAST [b][pix][100] for a cache-friendly dmll.
// ---------------------------------------------------------------------------
__global__ __launch_bounds__(256) void ninout_k(
    const float* __restrict__ ul, const unsigned short* __restrict__ wbn,
    const float* __restrict__ bias, float* __restrict__ params)
{
    constexpr int KCP = 40;
    __shared__ __align__(16) unsigned short bs[256 * KCP];
    __shared__ __align__(16) unsigned short wsm[32 * KCP];

    const int tid = threadIdx.x;
    const int wv = tid >> 6;
    const int lane = tid & 63;
    const int l16 = lane & 15;
    const int quad = lane >> 4;
    const int m0 = blockIdx.x * 32;
    const int bimg = blockIdx.y >> 2;
    const int rowbase = (blockIdx.y & 3) * 8;

    f32x4 acc[2][4];
#pragma unroll
    for (int mt = 0; mt < 2; ++mt)
#pragma unroll
        for (int ng = 0; ng < 4; ++ng)
#pragma unroll
            for (int r = 0; r < 4; ++r) acc[mt][ng][r] = 0.f;

    for (int k0 = 0; k0 < 160; k0 += 32) {
        __syncthreads();
        for (int e = tid; e < 256 * 8; e += 256) {
            int s = e & 7;
            int p = e >> 3;
            int pix = ((rowbase + (p >> 5)) << 5) | (p & 31);
            f32x4 xv = *(const f32x4*)(ul + (size_t)(((bimg << 10) | pix)) * 160 + k0 + s * 4);
            u16x4 st;
#pragma unroll
            for (int t = 0; t < 4; ++t) {
                float v = xv[t];
                st[t] = f2bf(v > 0.f ? v : expm1f(v));
            }
            *(u16x4*)(bs + p * KCP + s * 4) = st;
        }
        for (int e = tid; e < 32 * 4; e += 256) {
            int seg = e & 3;
            int mm = e >> 2;
            bf16x8 v = *(const bf16x8*)(wbn + (size_t)(m0 + mm) * 160 + k0 + seg * 8);
            *(bf16x8*)(wsm + mm * KCP + seg * 8) = v;
        }
        __syncthreads();
        bf16x8 af[2];
#pragma unroll
        for (int mt = 0; mt < 2; ++mt)
            af[mt] = *(const bf16x8*)&wsm[(mt * 16 + l16) * KCP + quad * 8];
#pragma unroll
        for (int ng = 0; ng < 4; ++ng) {
            int rl = 2 * wv + (ng >> 1);
            int cc = (ng & 1) * 16 + l16;
            bf16x8 bfr = *(const bf16x8*)&bs[(rl * 32 + cc) * KCP + quad * 8];
#pragma unroll
            for (int mt = 0; mt < 2; ++mt)
                acc[mt][ng] = __builtin_amdgcn_mfma_f32_16x16x32_bf16(af[mt], bfr, acc[mt][ng], 0, 0, 0);
        }
    }
#pragma unroll
    for (int mt = 0; mt < 2; ++mt) {
        int o = m0 + mt * 16 + quad * 4;
        if (o < PCH) {
            f32x4 bv = *(const f32x4*)(bias + o);
#pragma unroll
            for (int ng = 0; ng < 4; ++ng) {
                int i = rowbase + 2 * wv + (ng >> 1);
                int j = (ng & 1) * 16 + l16;
                int pix = (i << 5) + j;
                f32x4 vv;
#pragma unroll
                for (int r = 0; r < 4; ++r) vv[r] = acc[mt][ng][r] + bv[r];
                *(f32x4*)(params + (size_t)(((bimg << 10) | pix)) * 100 + o) = vv;
            }
        }
    }
}

// ---------------------------------------------------------------------------
// DMLL — params now channel-last [b][pix][100]: each thread reads 400
// contiguous bytes (compiler merges adjacent unrolled loads to dwordx4).
// ---------------------------------------------------------------------------
__device__ __forceinline__ float softplus_f(float v) {
    return fmaxf(v, 0.f) + log1pf(expf(-fabsf(v)));
}
__device__ __forceinline__ float sigmoid_f(float v) { return 1.f / (1.f + expf(-v)); }
__device__ __forceinline__ float lpterm(float x, float m, float ls) {
    float inv = expf(-ls);
    float cen = x - m;
    float plus = inv * (cen + 0.00392156862745098f);
    float minv = inv * (cen - 0.00392156862745098f);
    float cdf_delta = sigmoid_f(plus) - sigmoid_f(minv);
    float log_cdf_plus = plus - softplus_f(plus);
    float log_om = -softplus_f(minv);
    float mid = inv * cen;
    float log_pdf_mid = mid - ls - 2.f * softplus_f(mid);
    float inner = (cdf_delta > 1e-5f) ? logf(fmaxf(cdf_delta, 1e-12f))
                                      : (log_pdf_mid - 4.848116389675623f);
    return (x < -0.999f) ? log_cdf_plus : ((x > 0.999f) ? log_om : inner);
}

__global__ __launch_bounds__(256) void dmll_k(
    const float* __restrict__ smp, const float* __restrict__ params,
    float* __restrict__ partials)
{
    int idx = blockIdx.x * 256 + threadIdx.x;
    int b = idx >> 10;
    int ij = idx & 1023;
    const float* P = params + (size_t)idx * 100;

    float x0 = smp[(((size_t)b * 3 + 0) << 10) + ij] * 2.f - 1.f;
    float x1 = smp[(((size_t)b * 3 + 1) << 10) + ij] * 2.f - 1.f;
    float x2 = smp[(((size_t)b * 3 + 2) << 10) + ij] * 2.f - 1.f;

    float logit[NMIX];
    float mx = -1e30f;
#pragma unroll
    for (int n = 0; n < NMIX; ++n) { logit[n] = P[n]; mx = fmaxf(mx, logit[n]); }
    float se = 0.f;
#pragma unroll
    for (int n = 0; n < NMIX; ++n) se += expf(logit[n] - mx);
    float lse_logit = mx + logf(se);

    float lp[NMIX];
    float lpmax = -1e30f;
#pragma unroll
    for (int n = 0; n < NMIX; ++n) {
        float mean0 = P[10 + n];
        float mean1 = P[40 + n];
        float mean2 = P[70 + n];
        float ls0 = fmaxf(P[20 + n], -7.f);
        float ls1 = fmaxf(P[50 + n], -7.f);
        float ls2 = fmaxf(P[80 + n], -7.f);
        float c0 = tanhf(P[30 + n]);
        float c1 = tanhf(P[60 + n]);
        float c2 = tanhf(P[90 + n]);
        float m0 = mean0;
        float m1 = mean1 + c0 * x0;
        float m2 = mean2 + c1 * x0 + c2 * x1;
        float s3 = lpterm(x0, m0, ls0) + lpterm(x1, m1, ls1) + lpterm(x2, m2, ls2);
        lp[n] = s3 + logit[n] - lse_logit;
        lpmax = fmaxf(lpmax, lp[n]);
    }
    float se2 = 0.f;
#pragma unroll
    for (int n = 0; n < NMIX; ++n) se2 += expf(lp[n] - lpmax);
    float v = lpmax + logf(se2);

#pragma unroll
    for (int off = 32; off > 0; off >>= 1) v += __shfl_down(v, off);
    __shared__ float red[4];
    int tid = threadIdx.x;
    if ((tid & 63) == 0) red[tid >> 6] = v;
    __syncthreads();
    if (tid == 0) partials[blockIdx.x] = red[0] + red[1] + red[2] + red[3];
}

__global__ void dmll_final_k(const float* __restrict__ partials, float* __restrict__ out)
{
    float v = partials[threadIdx.x];
#pragma unroll
    for (int off = 32; off > 0; off >>= 1) v += __shfl_down(v, off);
    __shared__ float red[2];
    if ((threadIdx.x & 63) == 0) red[threadIdx.x >> 6] = v;
    __syncthreads();
    if (threadIdx.x == 0) out[0] = red[0] + red[1];
}

// ---------------------------------------------------------------------------
extern "C" void kernel_launch(void* const* d_in, const int* in_sizes, int n_in,
                              void* d_out, int out_size, void* d_ws, size_t ws_size,
                              hipStream_t stream)
{
    const float* samples   = (const float*)d_in[0];
    const float* w_u_init  = (const float*)d_in[1];
    const float* b_u_init  = (const float*)d_in[2];
    const float* w_ul_d    = (const float*)d_in[3];
    const float* b_ul_d    = (const float*)d_in[4];
    const float* w_ul_dr   = (const float*)d_in[5];
    const float* b_ul_dr   = (const float*)d_in[6];
    const float* u_c1_w    = (const float*)d_in[7];
    const float* u_c1_b    = (const float*)d_in[8];
    const float* u_c2_w    = (const float*)d_in[9];
    const float* u_c2_b    = (const float*)d_in[10];
    const float* ul_c1_w   = (const float*)d_in[11];
    const float* ul_c1_b   = (const float*)d_in[12];
    const float* ul_nin_w  = (const float*)d_in[13];
    const float* ul_nin_b  = (const float*)d_in[14];
    const float* ul_c2_w   = (const float*)d_in[15];
    const float* ul_c2_b   = (const float*)d_in[16];
    const float* nin_out_w = (const float*)d_in[17];
    const float* nin_out_b = (const float*)d_in[18];
    float* out = (float*)d_out;

    const size_t NU = (size_t)BZ * FCH * 1024;  // 5,242,880
    float* u  = (float*)d_ws;                    // [b][pix][160]
    float* ul = u + NU;
    unsigned short* CEu  = (unsigned short*)(ul + NU);   // [b][pix][320]
    unsigned short* CEc1 = CEu + 2 * NU;
    unsigned short* CEul = CEc1 + 2 * NU;
    unsigned short* WBu1  = CEul + 2 * NU;
    unsigned short* WBu2  = WBu1 + (size_t)5 * 160 * 6 * 320;
    unsigned short* WBul1 = WBu2 + (size_t)5 * 320 * 6 * 320;
    unsigned short* WBnin = WBul1 + (size_t)5 * 160 * 4 * 320;
    unsigned short* WBul2 = WBnin + (size_t)5 * 160 * 1 * 320;
    unsigned short* WBnout = WBul2 + (size_t)5 * 320 * 4 * 320;
    float* partials = (float*)(WBnout + (size_t)128 * 160);
    float* params = (float*)CEc1;  // [b][pix][100]; CEc1 dead once ninout runs

    dim3 blk(256);

    repack_t_k<<<800,  blk, 0, stream>>>(u_c1_w,    WBu1,  160, 160, 320, 6, 1);
    repack_t_k<<<1600, blk, 0, stream>>>(u_c2_w,    WBu2,  320, 320, 320, 6, 1);
    repack_t_k<<<800,  blk, 0, stream>>>(ul_c1_w,   WBul1, 160, 160, 320, 4, 1);
    repack_t_k<<<800,  blk, 0, stream>>>(ul_nin_w,  WBnin, 160, 160, 320, 1, 1);
    repack_t_k<<<1600, blk, 0, stream>>>(ul_c2_w,   WBul2, 320, 320, 320, 4, 1);
    repack_t_k<<<128,  blk, 0, stream>>>(nin_out_w, WBnout, 100, 128, 160, 1, 0);

    init_fused_k<<<dim3(8, 32), blk, 0, stream>>>(
        samples, w_u_init, b_u_init, w_ul_d, b_ul_d, w_ul_dr, b_ul_dr,
        u, ul, CEu, CEul);

    for (int t = 0; t < 5; ++t) {
        conv_mfma_k<2, 3, 1, 1, false, false, 32><<<dim3(5, 128), blk, 0, stream>>>(
            CEu, WBu1 + (size_t)t * 160 * 6 * 320, nullptr, nullptr,
            u_c1_b + t * 160, nullptr, nullptr, CEc1);
        conv_mfma_k<2, 3, 1, 1, false, true, 64><<<dim3(5, 128), blk, 0, stream>>>(
            CEc1, WBu2 + (size_t)t * 320 * 6 * 320, nullptr, nullptr,
            u_c2_b + t * 320, nullptr, u, CEu);
        conv_mfma_k<2, 2, 1, 1, true, false, 32><<<dim3(5, 128), blk, 0, stream>>>(
            CEul, WBul1 + (size_t)t * 160 * 4 * 320, CEu, WBnin + (size_t)t * 160 * 320,
            ul_c1_b + t * 160, ul_nin_b + t * 160, nullptr, CEc1);
        conv_mfma_k<2, 2, 1, 1, false, true, 64><<<dim3(5, 128), blk, 0, stream>>>(
            CEc1, WBul2 + (size_t)t * 320 * 4 * 320, nullptr, nullptr,
            ul_c2_b + t * 320, nullptr, ul, CEul);
    }

    ninout_k<<<dim3(4, 128), blk, 0, stream>>>(ul, WBnout, nin_out_b, params);
    dmll_k<<<128, blk, 0, stream>>>(samples, params, partials);
    dmll_final_k<<<1, 128, 0, stream>>>(partials, out);
}

// Round 5
// 1888.866 us; speedup vs baseline: 1.1103x; 1.1103x over previous
//
#include <hip/hip_runtime.h>
#include <math.h>

#define BZ 32
#define FCH 160
#define NMIX 10
#define PCH 100

typedef __attribute__((ext_vector_type(8))) short bf16x8;
typedef __attribute__((ext_vector_type(8))) unsigned short u16x8;
typedef __attribute__((ext_vector_type(4))) unsigned short u16x4;
typedef __attribute__((ext_vector_type(4))) float f32x4;

__device__ __forceinline__ unsigned short f2bf(float f) {
    union { float f; unsigned u; } x; x.f = f;
    return (unsigned short)((x.u + 0x7FFFu + ((x.u >> 16) & 1u)) >> 16);
}
__device__ __forceinline__ void elupair(float v, float& e0, float& e1) {
    if (v > 0.f) { e0 = v; e1 = expm1f(-v); }
    else         { e0 = expm1f(v); e1 = -v; }
}

// ---------------------------------------------------------------------------
// Weight repack via LDS: one block per (nb, o) row.
// w[nb][o][Cin][NT] fp32 -> wb[nb][o][NT][Cin] bf16; optional CE interleave.
// ---------------------------------------------------------------------------
__global__ __launch_bounds__(256) void repack_t_k(
    const float* __restrict__ w, unsigned short* __restrict__ wb,
    int Cout, int CoutPad, int Cin, int NT, int ILV)
{
    __shared__ float buf[1920];
    const int tid = threadIdx.x;
    const int blk = blockIdx.x;
    const int o = blk % CoutPad;
    const int nb = blk / CoutPad;
    const int n = Cin * NT;
    if (o < Cout) {
        const float* src = w + ((size_t)nb * Cout + o) * n;
        for (int e = tid; e < n; e += 256) buf[e] = src[e];
    } else {
        for (int e = tid; e < n; e += 256) buf[e] = 0.f;
    }
    __syncthreads();
    unsigned short* dst = wb + (size_t)blk * n;
    for (int tap = 0; tap < NT; ++tap)
        for (int k = tid; k < Cin; k += 256) {
            int csrc = ILV ? ((k & 1) * (Cin >> 1) + (k >> 1)) : k;
            dst[tap * Cin + k] = f2bf(buf[csrc * NT + tap]);
        }
}

// ---------------------------------------------------------------------------
// Fused init (round-4, kept): u-init + ul-init + both CE tensors in one pass.
// ---------------------------------------------------------------------------
__global__ __launch_bounds__(256) void init_fused_k(
    const float* __restrict__ smp,
    const float* __restrict__ wu_g, const float* __restrict__ bu_g,
    const float* __restrict__ wd_g, const float* __restrict__ bd_g,
    const float* __restrict__ wr_g, const float* __restrict__ br_g,
    float* __restrict__ u, float* __restrict__ ul,
    unsigned short* __restrict__ ceu, unsigned short* __restrict__ ceul)
{
    __shared__ float xs[4 * 6 * 34];
    __shared__ float wuL[160 * 25];
    __shared__ float wdL[160 * 13];
    __shared__ float wrL[160 * 9];
    __shared__ float bL[3 * 160];

    const int tid = threadIdx.x;
    const int b = blockIdx.y;
    const int rb = blockIdx.x * 4;

    for (int e = tid; e < 816; e += 256) {
        int c = e / 204;
        int rem = e - c * 204;
        int r = rem / 34;
        int col = rem - r * 34;
        int gr = rb - 2 + r, gc = col - 1;
        float v = 0.f;
        if ((unsigned)gr < 32u && (unsigned)gc < 32u)
            v = (c < 3) ? smp[(((size_t)b * 3 + c) << 10) + (gr << 5) + gc] * 2.f - 1.f : 1.f;
        xs[e] = v;
    }
    for (int e = tid; e < 160 * 24; e += 256) wuL[(e / 24) * 25 + e % 24] = wu_g[e];
    for (int e = tid; e < 160 * 12; e += 256) wdL[(e / 12) * 13 + e % 12] = wd_g[e];
    for (int e = tid; e < 160 * 8;  e += 256) wrL[(e / 8) * 9 + e % 8] = wr_g[e];
    for (int e = tid; e < 160; e += 256) {
        bL[e] = bu_g[e]; bL[160 + e] = bd_g[e]; bL[320 + e] = br_g[e];
    }
    __syncthreads();

    for (int it = 0; it < 20; ++it) {
        int item = tid + it * 256;
        int og = item % 40;
        int p = item / 40;
        int lr = p >> 5, j = p & 31;
        int i = rb + lr;
        size_t pixbase = (size_t)((b << 10) | (i << 5) | j);
#pragma unroll
        for (int t = 0; t < 4; ++t) {
            int o = og + 40 * t;
            float au = 0.f;
            const float* wo = &wuL[o * 25];
#pragma unroll
            for (int c = 0; c < 4; ++c)
#pragma unroll
                for (int kh = 0; kh < 2; ++kh)
#pragma unroll
                    for (int kw = 0; kw < 3; ++kw)
                        au += wo[c * 6 + kh * 3 + kw] * xs[c * 204 + (lr + kh) * 34 + (j + kw)];
            float uv = (i == 0) ? 0.f : (au + bL[o]);
            float ad = 0.f;
            const float* wdp = &wdL[o * 13];
#pragma unroll
            for (int c = 0; c < 4; ++c)
#pragma unroll
                for (int kw = 0; kw < 3; ++kw)
                    ad += wdp[c * 3 + kw] * xs[c * 204 + (lr + 1) * 34 + (j + kw)];
            float ar = 0.f;
            const float* wrp = &wrL[o * 9];
#pragma unroll
            for (int c = 0; c < 4; ++c)
#pragma unroll
                for (int kh = 0; kh < 2; ++kh)
                    ar += wrp[c * 2 + kh] * xs[c * 204 + (lr + 1 + kh) * 34 + j];
            float ulv = ((i >= 1) ? ad + bL[160 + o] : 0.f) + ((j >= 1) ? ar + bL[320 + o] : 0.f);

            u[pixbase * 160 + o] = uv;
            ul[pixbase * 160 + o] = ulv;
            float e0, e1;
            elupair(uv, e0, e1);
            ((unsigned*)ceu)[pixbase * 160 + o] = (unsigned)f2bf(e0) | ((unsigned)f2bf(e1) << 16);
            elupair(ulv, e0, e1);
            ((unsigned*)ceul)[pixbase * 160 + o] = (unsigned)f2bf(e0) | ((unsigned)f2bf(e1) << 16);
        }
    }
}

// ---------------------------------------------------------------------------
// MFMA implicit-GEMM conv, restructured K-loop:
//  - A (weight) fragments loaded DIRECTLY from global per lane (L2-resident),
//    no weight LDS tile.
//  - B tile double-buffered in LDS: prefetch chunk k+1 before MFMA on chunk k,
//    ONE barrier per chunk.
// ---------------------------------------------------------------------------
template<int KH, int KW, int PT, int PL, bool DUAL, bool GATE, int MBLK>
__global__ __launch_bounds__(256) void conv_mfma_k(
    const unsigned short* __restrict__ cein,
    const unsigned short* __restrict__ wb,
    const unsigned short* __restrict__ cein2,
    const unsigned short* __restrict__ wb2,
    const float* __restrict__ bias, const float* __restrict__ bias2,
    float* __restrict__ resid,
    unsigned short* __restrict__ ceout)
{
    constexpr int NT = KH * KW;
    constexpr int RW = 8 + KH - 1;
    constexpr int CW = 32 + KW - 1;
    constexpr int KCP = 40;
    constexpr int MTILES = MBLK / 16;

    __shared__ __align__(16) unsigned short bs[2][RW * CW * KCP];

    const int tid = threadIdx.x;
    const int wv = tid >> 6;
    const int lane = tid & 63;
    const int l16 = lane & 15;
    const int quad = lane >> 4;
    const int m0 = blockIdx.x * 32;
    const int bimg = blockIdx.y >> 2;
    const int rowbase = (blockIdx.y & 3) * 8;

    // per-tile A base offsets (halfwords): row o+l16, k-segment quad*8
    size_t abase[MTILES];
#pragma unroll
    for (int mt = 0; mt < MTILES; ++mt) {
        int o = GATE ? (mt < MTILES / 2 ? m0 + mt * 16 : 160 + m0 + (mt - MTILES / 2) * 16)
                     : (m0 + mt * 16);
        abase[mt] = (size_t)(o + l16) * NT * 320 + quad * 8;
    }

    f32x4 acc[MTILES][4];
#pragma unroll
    for (int mt = 0; mt < MTILES; ++mt)
#pragma unroll
        for (int ng = 0; ng < 4; ++ng)
#pragma unroll
            for (int r = 0; r < 4; ++r) acc[mt][ng][r] = 0.f;

    auto stage_main = [&](int k0, int buf) {
        unsigned short* d = (unsigned short*)bs[buf];
        for (int e = tid; e < RW * CW * 4; e += 256) {
            int seg = e & 3;
            int p = e >> 2;
            int r = p / CW;
            int c = p - r * CW;
            int grow = rowbase + r - PT;
            int gcol = c - PL;
            bf16x8 v = {0, 0, 0, 0, 0, 0, 0, 0};
            if (((unsigned)grow < 32u) && ((unsigned)gcol < 32u))
                v = *(const bf16x8*)(cein +
                    (size_t)(((bimg << 10) | (grow << 5) | gcol)) * 320 + k0 + seg * 8);
            *(bf16x8*)(d + p * KCP + seg * 8) = v;
        }
    };
    auto stage_nin = [&](int k0, int buf) {
        unsigned short* d = (unsigned short*)bs[buf];
        for (int e = tid; e < 8 * 32 * 4; e += 256) {
            int seg = e & 3;
            int p = e >> 2;
            int r = p >> 5, c = p & 31;
            bf16x8 v = *(const bf16x8*)(cein2 +
                (size_t)(((bimg << 10) | ((rowbase + r) << 5) | c)) * 320 + k0 + seg * 8);
            *(bf16x8*)(d + (r * CW + c) * KCP + seg * 8) = v;
        }
    };

    stage_main(0, 0);
    for (int kc = 0; kc < 10; ++kc) {
        const int cur = kc & 1;
        __syncthreads();
        if (kc < 9) stage_main((kc + 1) * 32, cur ^ 1);
        else if (DUAL) stage_nin(0, cur ^ 1);
        const unsigned short* bsc = bs[cur];
        const int k0 = kc * 32;
#pragma unroll
        for (int tap = 0; tap < NT; ++tap) {
            const int kh = tap / KW, kw = tap % KW;
            bf16x8 af[MTILES];
#pragma unroll
            for (int mt = 0; mt < MTILES; ++mt)
                af[mt] = *(const bf16x8*)(wb + abase[mt] + (size_t)tap * 320 + k0);
#pragma unroll
            for (int ng = 0; ng < 4; ++ng) {
                int rl = 2 * wv + (ng >> 1) + kh;
                int cc = (ng & 1) * 16 + l16 + kw;
                bf16x8 bfr = *(const bf16x8*)&bsc[(rl * CW + cc) * KCP + quad * 8];
#pragma unroll
                for (int mt = 0; mt < MTILES; ++mt)
                    acc[mt][ng] = __builtin_amdgcn_mfma_f32_16x16x32_bf16(af[mt], bfr, acc[mt][ng], 0, 0, 0);
            }
        }
    }

    if (DUAL) {  // fused 1x1 nin over second CE input (non-GATE, MBLK=32)
        size_t abase2[MTILES];
#pragma unroll
        for (int mt = 0; mt < MTILES; ++mt)
            abase2[mt] = (size_t)(m0 + mt * 16 + l16) * 320 + quad * 8;
        for (int kc = 0; kc < 10; ++kc) {
            const int cur = kc & 1;
            __syncthreads();
            if (kc < 9) stage_nin((kc + 1) * 32, cur ^ 1);
            const unsigned short* bsc = bs[cur];
            const int k0 = kc * 32;
            bf16x8 af[MTILES];
#pragma unroll
            for (int mt = 0; mt < MTILES; ++mt)
                af[mt] = *(const bf16x8*)(wb2 + abase2[mt] + k0);
#pragma unroll
            for (int ng = 0; ng < 4; ++ng) {
                int rl = 2 * wv + (ng >> 1);
                int cc = (ng & 1) * 16 + l16;
                bf16x8 bfr = *(const bf16x8*)&bsc[(rl * CW + cc) * KCP + quad * 8];
#pragma unroll
                for (int mt = 0; mt < MTILES; ++mt)
                    acc[mt][ng] = __builtin_amdgcn_mfma_f32_16x16x32_bf16(af[mt], bfr, acc[mt][ng], 0, 0, 0);
            }
        }
    }

    // ---- epilogue (channel-last CE / resid, as in rounds 3-4)
    constexpr int MOUT = GATE ? MTILES / 2 : MTILES;
#pragma unroll
    for (int mt = 0; mt < MOUT; ++mt) {
        int ob = m0 + mt * 16 + quad * 4;
        f32x4 bv = *(const f32x4*)(bias + ob);
        f32x4 bv2;
        if (DUAL) bv2 = *(const f32x4*)(bias2 + ob);
        f32x4 bg;
        if (GATE) bg = *(const f32x4*)(bias + ob + 160);
#pragma unroll
        for (int ng = 0; ng < 4; ++ng) {
            int i = rowbase + 2 * wv + (ng >> 1);
            int j = (ng & 1) * 16 + l16;
            size_t pb = (size_t)((bimg << 10) | (i << 5) | j);
            if (!GATE) {
                u16x8 st;
#pragma unroll
                for (int r = 0; r < 4; ++r) {
                    float v = acc[mt][ng][r] + bv[r] + (DUAL ? bv2[r] : 0.f);
                    float e0, e1; elupair(v, e0, e1);
                    st[2 * r] = f2bf(e0); st[2 * r + 1] = f2bf(e1);
                }
                *(u16x8*)(ceout + pb * 320 + 2 * ob) = st;
            } else {
                f32x4 rv = *(const f32x4*)(resid + pb * 160 + ob);
                u16x8 st;
#pragma unroll
                for (int r = 0; r < 4; ++r) {
                    float g1 = acc[mt][ng][r] + bv[r];
                    float g2 = acc[mt + MTILES / 2][ng][r] + bg[r];
                    float v = rv[r] + g1 / (1.f + expf(-g2));
                    rv[r] = v;
                    float e0, e1; elupair(v, e0, e1);
                    st[2 * r] = f2bf(e0); st[2 * r + 1] = f2bf(e1);
                }
                *(f32x4*)(resid + pb * 160 + ob) = rv;
                *(u16x8*)(ceout + pb * 320 + 2 * ob) = st;
            }
        }
    }
}

// ---------------------------------------------------------------------------
// nin_out: params = elu(ul) @ W^T + b, K=160, M padded to 128.
// Direct-A from global; params CHANNEL-MAJOR [b][100][1024] (coalesced, and
// dmll reads it coalesced too).
// ---------------------------------------------------------------------------
__global__ __launch_bounds__(256) void ninout_k(
    const float* __restrict__ ul, const unsigned short* __restrict__ wbn,
    const float* __restrict__ bias, float* __restrict__ params)
{
    constexpr int KCP = 40;
    __shared__ __align__(16) unsigned short bsm[256 * KCP];

    const int tid = threadIdx.x;
    const int wv = tid >> 6;
    const int lane = tid & 63;
    const int l16 = lane & 15;
    const int quad = lane >> 4;
    const int m0 = blockIdx.x * 32;
    const int bimg = blockIdx.y >> 2;
    const int rowbase = (blockIdx.y & 3) * 8;

    f32x4 acc[2][4];
#pragma unroll
    for (int mt = 0; mt < 2; ++mt)
#pragma unroll
        for (int ng = 0; ng < 4; ++ng)
#pragma unroll
            for (int r = 0; r < 4; ++r) acc[mt][ng][r] = 0.f;

    size_t abase[2];
#pragma unroll
    for (int mt = 0; mt < 2; ++mt)
        abase[mt] = (size_t)(m0 + mt * 16 + l16) * 160 + quad * 8;

    for (int k0 = 0; k0 < 160; k0 += 32) {
        __syncthreads();
        for (int e = tid; e < 256 * 8; e += 256) {
            int s = e & 7;
            int p = e >> 3;
            int pix = ((rowbase + (p >> 5)) << 5) | (p & 31);
            f32x4 xv = *(const f32x4*)(ul + (size_t)(((bimg << 10) | pix)) * 160 + k0 + s * 4);
            u16x4 st;
#pragma unroll
            for (int t = 0; t < 4; ++t) {
                float v = xv[t];
                st[t] = f2bf(v > 0.f ? v : expm1f(v));
            }
            *(u16x4*)(bsm + p * KCP + s * 4) = st;
        }
        __syncthreads();
        bf16x8 af[2];
#pragma unroll
        for (int mt = 0; mt < 2; ++mt)
            af[mt] = *(const bf16x8*)(wbn + abase[mt] + k0);
#pragma unroll
        for (int ng = 0; ng < 4; ++ng) {
            int rl = 2 * wv + (ng >> 1);
            int cc = (ng & 1) * 16 + l16;
            bf16x8 bfr = *(const bf16x8*)&bsm[(rl * 32 + cc) * KCP + quad * 8];
#pragma unroll
            for (int mt = 0; mt < 2; ++mt)
                acc[mt][ng] = __builtin_amdgcn_mfma_f32_16x16x32_bf16(af[mt], bfr, acc[mt][ng], 0, 0, 0);
        }
    }
#pragma unroll
    for (int mt = 0; mt < 2; ++mt)
#pragma unroll
        for (int ng = 0; ng < 4; ++ng) {
            int i = rowbase + 2 * wv + (ng >> 1);
            int j = (ng & 1) * 16 + l16;
            int pix = (i << 5) + j;
#pragma unroll
            for (int r = 0; r < 4; ++r) {
                int o = m0 + mt * 16 + quad * 4 + r;
                if (o < PCH)
                    params[(((size_t)bimg * PCH + o) << 10) + pix] = acc[mt][ng][r] + bias[o];
            }
        }
}

// ---------------------------------------------------------------------------
// DMLL — channel-major params (per-instruction coalesced). 128-thread blocks
// for better CU spread.
// ---------------------------------------------------------------------------
__device__ __forceinline__ float softplus_f(float v) {
    return fmaxf(v, 0.f) + log1pf(expf(-fabsf(v)));
}
__device__ __forceinline__ float sigmoid_f(float v) { return 1.f / (1.f + expf(-v)); }
__device__ __forceinline__ float lpterm(float x, float m, float ls) {
    float inv = expf(-ls);
    float cen = x - m;
    float plus = inv * (cen + 0.00392156862745098f);
    float minv = inv * (cen - 0.00392156862745098f);
    float cdf_delta = sigmoid_f(plus) - sigmoid_f(minv);
    float log_cdf_plus = plus - softplus_f(plus);
    float log_om = -softplus_f(minv);
    float mid = inv * cen;
    float log_pdf_mid = mid - ls - 2.f * softplus_f(mid);
    float inner = (cdf_delta > 1e-5f) ? logf(fmaxf(cdf_delta, 1e-12f))
                                      : (log_pdf_mid - 4.848116389675623f);
    return (x < -0.999f) ? log_cdf_plus : ((x > 0.999f) ? log_om : inner);
}

__global__ __launch_bounds__(128) void dmll_k(
    const float* __restrict__ smp, const float* __restrict__ params,
    float* __restrict__ partials)
{
    int idx = blockIdx.x * 128 + threadIdx.x;
    int b = idx >> 10;
    int ij = idx & 1023;
    const float* P = params + ((size_t)b * PCH << 10) + ij;

    float x0 = smp[(((size_t)b * 3 + 0) << 10) + ij] * 2.f - 1.f;
    float x1 = smp[(((size_t)b * 3 + 1) << 10) + ij] * 2.f - 1.f;
    float x2 = smp[(((size_t)b * 3 + 2) << 10) + ij] * 2.f - 1.f;

    float logit[NMIX];
    float mx = -1e30f;
#pragma unroll
    for (int n = 0; n < NMIX; ++n) { logit[n] = P[(size_t)n << 10]; mx = fmaxf(mx, logit[n]); }
    float se = 0.f;
#pragma unroll
    for (int n = 0; n < NMIX; ++n) se += expf(logit[n] - mx);
    float lse_logit = mx + logf(se);

    float lp[NMIX];
    float lpmax = -1e30f;
#pragma unroll
    for (int n = 0; n < NMIX; ++n) {
        float mean0 = P[(size_t)(10 + n) << 10];
        float mean1 = P[(size_t)(40 + n) << 10];
        float mean2 = P[(size_t)(70 + n) << 10];
        float ls0 = fmaxf(P[(size_t)(20 + n) << 10], -7.f);
        float ls1 = fmaxf(P[(size_t)(50 + n) << 10], -7.f);
        float ls2 = fmaxf(P[(size_t)(80 + n) << 10], -7.f);
        float c0 = tanhf(P[(size_t)(30 + n) << 10]);
        float c1 = tanhf(P[(size_t)(60 + n) << 10]);
        float c2 = tanhf(P[(size_t)(90 + n) << 10]);
        float m0 = mean0;
        float m1 = mean1 + c0 * x0;
        float m2 = mean2 + c1 * x0 + c2 * x1;
        float s3 = lpterm(x0, m0, ls0) + lpterm(x1, m1, ls1) + lpterm(x2, m2, ls2);
        lp[n] = s3 + logit[n] - lse_logit;
        lpmax = fmaxf(lpmax, lp[n]);
    }
    float se2 = 0.f;
#pragma unroll
    for (int n = 0; n < NMIX; ++n) se2 += expf(lp[n] - lpmax);
    float v = lpmax + logf(se2);

#pragma unroll
    for (int off = 32; off > 0; off >>= 1) v += __shfl_down(v, off);
    __shared__ float red[2];
    int tid = threadIdx.x;
    if ((tid & 63) == 0) red[tid >> 6] = v;
    __syncthreads();
    if (tid == 0) partials[blockIdx.x] = red[0] + red[1];
}

__global__ __launch_bounds__(256) void dmll_final_k(
    const float* __restrict__ partials, float* __restrict__ out)
{
    float v = partials[threadIdx.x];  // 256 partials
#pragma unroll
    for (int off = 32; off > 0; off >>= 1) v += __shfl_down(v, off);
    __shared__ float red[4];
    if ((threadIdx.x & 63) == 0) red[threadIdx.x >> 6] = v;
    __syncthreads();
    if (threadIdx.x == 0) out[0] = red[0] + red[1] + red[2] + red[3];
}

// ---------------------------------------------------------------------------
extern "C" void kernel_launch(void* const* d_in, const int* in_sizes, int n_in,
                              void* d_out, int out_size, void* d_ws, size_t ws_size,
                              hipStream_t stream)
{
    const float* samples   = (const float*)d_in[0];
    const float* w_u_init  = (const float*)d_in[1];
    const float* b_u_init  = (const float*)d_in[2];
    const float* w_ul_d    = (const float*)d_in[3];
    const float* b_ul_d    = (const float*)d_in[4];
    const float* w_ul_dr   = (const float*)d_in[5];
    const float* b_ul_dr   = (const float*)d_in[6];
    const float* u_c1_w    = (const float*)d_in[7];
    const float* u_c1_b    = (const float*)d_in[8];
    const float* u_c2_w    = (const float*)d_in[9];
    const float* u_c2_b    = (const float*)d_in[10];
    const float* ul_c1_w   = (const float*)d_in[11];
    const float* ul_c1_b   = (const float*)d_in[12];
    const float* ul_nin_w  = (const float*)d_in[13];
    const float* ul_nin_b  = (const float*)d_in[14];
    const float* ul_c2_w   = (const float*)d_in[15];
    const float* ul_c2_b   = (const float*)d_in[16];
    const float* nin_out_w = (const float*)d_in[17];
    const float* nin_out_b = (const float*)d_in[18];
    float* out = (float*)d_out;

    const size_t NU = (size_t)BZ * FCH * 1024;  // 5,242,880
    float* u  = (float*)d_ws;                    // [b][pix][160]
    float* ul = u + NU;
    unsigned short* CEu  = (unsigned short*)(ul + NU);   // [b][pix][320]
    unsigned short* CEc1 = CEu + 2 * NU;
    unsigned short* CEul = CEc1 + 2 * NU;
    unsigned short* WBu1  = CEul + 2 * NU;
    unsigned short* WBu2  = WBu1 + (size_t)5 * 160 * 6 * 320;
    unsigned short* WBul1 = WBu2 + (size_t)5 * 320 * 6 * 320;
    unsigned short* WBnin = WBul1 + (size_t)5 * 160 * 4 * 320;
    unsigned short* WBul2 = WBnin + (size_t)5 * 160 * 1 * 320;
    unsigned short* WBnout = WBul2 + (size_t)5 * 320 * 4 * 320;
    float* partials = (float*)(WBnout + (size_t)128 * 160);
    float* params = (float*)CEc1;  // [b][100][1024]; CEc1 dead once ninout runs

    dim3 blk(256);

    repack_t_k<<<800,  blk, 0, stream>>>(u_c1_w,    WBu1,  160, 160, 320, 6, 1);
    repack_t_k<<<1600, blk, 0, stream>>>(u_c2_w,    WBu2,  320, 320, 320, 6, 1);
    repack_t_k<<<800,  blk, 0, stream>>>(ul_c1_w,   WBul1, 160, 160, 320, 4, 1);
    repack_t_k<<<800,  blk, 0, stream>>>(ul_nin_w,  WBnin, 160, 160, 320, 1, 1);
    repack_t_k<<<1600, blk, 0, stream>>>(ul_c2_w,   WBul2, 320, 320, 320, 4, 1);
    repack_t_k<<<128,  blk, 0, stream>>>(nin_out_w, WBnout, 100, 128, 160, 1, 0);

    init_fused_k<<<dim3(8, 32), blk, 0, stream>>>(
        samples, w_u_init, b_u_init, w_ul_d, b_ul_d, w_ul_dr, b_ul_dr,
        u, ul, CEu, CEul);

    for (int t = 0; t < 5; ++t) {
        conv_mfma_k<2, 3, 1, 1, false, false, 32><<<dim3(5, 128), blk, 0, stream>>>(
            CEu, WBu1 + (size_t)t * 160 * 6 * 320, nullptr, nullptr,
            u_c1_b + t * 160, nullptr, nullptr, CEc1);
        conv_mfma_k<2, 3, 1, 1, false, true, 64><<<dim3(5, 128), blk, 0, stream>>>(
            CEc1, WBu2 + (size_t)t * 320 * 6 * 320, nullptr, nullptr,
            u_c2_b + t * 320, nullptr, u, CEu);
        conv_mfma_k<2, 2, 1, 1, true, false, 32><<<dim3(5, 128), blk, 0, stream>>>(
            CEul, WBul1 + (size_t)t * 160 * 4 * 320, CEu, WBnin + (size_t)t * 160 * 320,
            ul_c1_b + t * 160, ul_nin_b + t * 160, nullptr, CEc1);
        conv_mfma_k<2, 2, 1, 1, false, true, 64><<<dim3(5, 128), blk, 0, stream>>>(
            CEc1, WBul2 + (size_t)t * 320 * 4 * 320, nullptr, nullptr,
            ul_c2_b + t * 320, nullptr, ul, CEul);
    }

    ninout_k<<<dim3(4, 128), blk, 0, stream>>>(ul, WBnout, nin_out_b, params);
    dmll_k<<<256, dim3(128), 0, stream>>>(samples, params, partials);
    dmll_final_k<<<1, blk, 0, stream>>>(partials, out);
}